// Round 6
// baseline (11158.857 us; speedup 1.0000x reference)
//
#include <hip/hip_runtime.h>
#include <hip/hip_bf16.h>
#include <math.h>

using u16 = unsigned short;
using u32 = unsigned int;

__device__ __forceinline__ float bf2f(u16 u) {
    u32 x = ((u32)u) << 16;
    return __builtin_bit_cast(float, x);
}
__device__ __forceinline__ u16 f2bf(float f) {
    u32 x = __builtin_bit_cast(u32, f);
    x += 0x7fffu + ((x >> 16) & 1u);
    return (u16)(x >> 16);
}

// ---------------------------------------------------------------- GEMM ----
// C[M,N] = A[M,K] @ B[K,N]. A/B: f32 or internal bf16 per flags; f32
// accumulate; C: f32 or bf16 per OUT_F32; optional ELU epilogue.
// BM=BN=64, BK=16, 256 threads, 4x4 microtile. Bounds-checked everywhere.
template<bool A_F32, bool B_F32, bool DO_ELU, bool OUT_F32>
__global__ __launch_bounds__(256) void sgemm(
    const void* __restrict__ Av, const void* __restrict__ Bv,
    void* __restrict__ Cv, int M, int N, int K)
{
    constexpr int BM = 64, BN = 64, BK = 16;
    __shared__ float As[BK][BM + 1];
    __shared__ float Bs[BK][BN + 1];
    const int bm0 = blockIdx.y * BM, bn0 = blockIdx.x * BN;
    const int tx = threadIdx.x & 15, ty = threadIdx.x >> 4;

    float acc[4][4] = {};

    for (int k0 = 0; k0 < K; k0 += BK) {
        for (int t = threadIdx.x; t < BM * BK; t += 256) {
            int m = t >> 4, k = t & 15;
            int gm = bm0 + m, gk = k0 + k;
            float v = 0.f;
            if (gm < M && gk < K) {
                size_t idx = (size_t)gm * K + gk;
                v = A_F32 ? ((const float*)Av)[idx] : bf2f(((const u16*)Av)[idx]);
            }
            As[k][m] = v;
        }
        for (int t = threadIdx.x; t < BK * BN; t += 256) {
            int k = t >> 6, n = t & 63;
            int gk = k0 + k, gn = bn0 + n;
            float v = 0.f;
            if (gk < K && gn < N) {
                size_t idx = (size_t)gk * N + gn;
                v = B_F32 ? ((const float*)Bv)[idx] : bf2f(((const u16*)Bv)[idx]);
            }
            Bs[k][n] = v;
        }
        __syncthreads();
#pragma unroll
        for (int k = 0; k < BK; k++) {
            float a[4], b[4];
#pragma unroll
            for (int i = 0; i < 4; i++) a[i] = As[k][ty * 4 + i];
#pragma unroll
            for (int j = 0; j < 4; j++) b[j] = Bs[k][tx * 4 + j];
#pragma unroll
            for (int i = 0; i < 4; i++)
#pragma unroll
                for (int j = 0; j < 4; j++) acc[i][j] += a[i] * b[j];
        }
        __syncthreads();
    }

#pragma unroll
    for (int i = 0; i < 4; i++)
#pragma unroll
        for (int j = 0; j < 4; j++) {
            int gm = bm0 + ty * 4 + i, gn = bn0 + tx * 4 + j;
            if (gm < M && gn < N) {
                float v = acc[i][j];
                if (DO_ELU) v = v > 0.f ? v : expm1f(v);
                if (OUT_F32) ((float*)Cv)[(size_t)gm * N + gn] = v;
                else         ((u16*)Cv)[(size_t)gm * N + gn] = f2bf(v);
            }
        }
}

// ------------------------------------------------------------- reduce ----
__device__ __forceinline__ float block_sum4(float v, float* red) {
#pragma unroll
    for (int off = 32; off; off >>= 1) v += __shfl_down(v, off);
    int w = threadIdx.x >> 6;
    if ((threadIdx.x & 63) == 0) red[w] = v;
    __syncthreads();
    float r = red[0] + red[1] + red[2] + red[3];
    __syncthreads();
    return r;
}
__device__ __forceinline__ float block_max4(float v, float* red) {
#pragma unroll
    for (int off = 32; off; off >>= 1) v = fmaxf(v, __shfl_down(v, off));
    int w = threadIdx.x >> 6;
    if ((threadIdx.x & 63) == 0) red[w] = v;
    __syncthreads();
    float r = fmaxf(fmaxf(red[0], red[1]), fmaxf(red[2], red[3]));
    __syncthreads();
    return r;
}

// ------------------------------------------------------------- scores ----
// s1[i] = sum_f Wh[i,f]*a[f]; s2[i] = sum_f Wh[i,f]*a[F+f].
// Wh internal bf16; a f32 (the reference's [2F,1] vector). Block per row.
__global__ __launch_bounds__(256) void scores_kernel(
    const u16* __restrict__ Wh, int ld, int F, const float* __restrict__ a,
    float* __restrict__ s1, float* __restrict__ s2)
{
    __shared__ float red[4];
    int i = blockIdx.x, tid = threadIdx.x;
    float acc1 = 0.f, acc2 = 0.f;
    for (int f = tid; f < F; f += 256) {
        float w = bf2f(Wh[(size_t)i * ld + f]);
        acc1 += w * a[f];
        acc2 += w * a[F + f];
    }
    acc1 = block_sum4(acc1, red);
    acc2 = block_sum4(acc2, red);
    if (tid == 0) { s1[i] = acc1; s2[i] = acc2; }
}

// ---------------------------------------------------------------- att ----
// att[i,:] = softmax_j over active j of lrelu(s1_i + s2_j); bf16 out.
__global__ __launch_bounds__(256) void att_kernel(
    const u32* __restrict__ mask, const float* __restrict__ s1,
    const float* __restrict__ s2, u16* __restrict__ att, int n)
{
    __shared__ float red[4];
    int i = blockIdx.x, tid = threadIdx.x;
    float s1i = s1[i];
    int j0 = tid * 16;
    u32 w = mask[(size_t)i * (n >> 5) + (j0 >> 5)];
    u32 bits = (j0 & 16) ? (w >> 16) : (w & 0xFFFFu);

    float e[16];
    float mx = -3.0e38f;
#pragma unroll
    for (int t = 0; t < 16; t++) {
        float x = s1i + s2[j0 + t];
        x = x > 0.f ? x : 0.2f * x;
        e[t] = x;
        if ((bits >> t) & 1u) mx = fmaxf(mx, x);
    }
    mx = block_max4(mx, red);

    float sum = 0.f;
#pragma unroll
    for (int t = 0; t < 16; t++) {
        float pv = ((bits >> t) & 1u) ? expf(e[t] - mx) : 0.f;
        e[t] = pv;
        sum += pv;
    }
    sum = block_sum4(sum, red);
    float rinv = sum > 0.f ? 1.f / sum : 0.f;
#pragma unroll
    for (int t = 0; t < 16; t++)
        att[(size_t)i * n + j0 + t] = f2bf(e[t] * rinv);
}

// --------------------------------------------------------------- fuse ----
// E1/E2 internal bf16 [N,64]; W [64,64] f32; U [64] f32. f32 outputs.
__global__ __launch_bounds__(64) void fuse_kernel(
    const u16* __restrict__ E1, const u16* __restrict__ E2,
    const float* __restrict__ W, const float* __restrict__ U,
    float* __restrict__ fused, float* __restrict__ alpha)
{
    __shared__ float e1[64], e2[64];
    int i = blockIdx.x, d = threadIdx.x;
    e1[d] = bf2f(E1[i * 64 + d]);
    e2[d] = bf2f(E2[i * 64 + d]);
    __syncthreads();
    float v1 = 0.f, v2 = 0.f;
#pragma unroll 8
    for (int f = 0; f < 64; f++) {
        float w = W[f * 64 + d];
        v1 += e1[f] * w;
        v2 += e2[f] * w;
    }
    v1 = tanhf(v1); v2 = tanhf(v2);
    float u = U[d];
    float p1 = v1 * u, p2 = v2 * u;
#pragma unroll
    for (int off = 32; off; off >>= 1) {
        p1 += __shfl_down(p1, off);
        p2 += __shfl_down(p2, off);
    }
    p1 = __shfl(p1, 0); p2 = __shfl(p2, 0);
    float m = fmaxf(p1, p2);
    float w1 = expf(p1 - m), w2 = expf(p2 - m);
    float a1 = w1 / (w1 + w2), a2 = w2 / (w1 + w2);
    fused[i * 64 + d] = a1 * e1[d] + a2 * e2[d];
    if (alpha != nullptr && d < 2) alpha[i * 2 + d] = (d == 0 ? a1 : a2);
}

// ------------------------------------------------------------- bitpack ----
__global__ void bitpack_kernel(const int* __restrict__ adj,
                               u32* __restrict__ mask, int nwords)
{
    int w = blockIdx.x * 256 + threadIdx.x;
    if (w >= nwords) return;
    const int* src = adj + (size_t)w * 32;
    u32 m = 0;
#pragma unroll
    for (int b = 0; b < 32; b++) m |= (src[b] > 0 ? 1u : 0u) << b;
    mask[w] = m;
}

// ------------------------------------------------------------- driver ----
extern "C" void kernel_launch(void* const* d_in, const int* in_sizes, int n_in,
                              void* d_out, int out_size, void* d_ws, size_t ws_size,
                              hipStream_t stream)
{
    const int N = 4096, DIN = 3000, DH = 512, DO = 64;
    const float* x      = (const float*)d_in[0];
    const int*   adjF   = (const int*)d_in[1];
    const int*   adjS   = (const int*)d_in[2];
    const float* We1    = (const float*)d_in[3];
    const float* aE1    = (const float*)d_in[4];
    const float* We2    = (const float*)d_in[5];
    const float* aE2    = (const float*)d_in[6];
    const float* Wd1    = (const float*)d_in[7];
    const float* aD1    = (const float*)d_in[8];
    const float* Wd2    = (const float*)d_in[9];
    const float* aD2    = (const float*)d_in[10];
    const float* Womega = (const float*)d_in[11];
    const float* Uomega = (const float*)d_in[12];

    // f32 outputs (reference returns float32 arrays)
    float* out       = (float*)d_out;
    float* out_emb   = out;                          // [4096,64]
    float* out_recon = out + (size_t)N * DO;         // [4096,3000]
    float* out_corr  = out_recon + (size_t)N * DIN;  // [4096,64]
    float* out_alpha = out_corr + (size_t)N * DO;    // [4096,2]

    char* ws = (char*)d_ws;
    size_t off = 0;
    auto alloc = [&](size_t bytes) {
        size_t o = off; off += (bytes + 255) & ~(size_t)255; return o;
    };
    const size_t o_att   = alloc((size_t)N * N * 2);        // 33.6 MB
    const size_t o_maskF = alloc((size_t)N * (N / 32) * 4); // 2.1 MB
    const size_t o_maskS = alloc((size_t)N * (N / 32) * 4);
    const size_t o_s1    = alloc((size_t)N * 4);
    const size_t o_s2    = alloc((size_t)N * 4);
    const size_t o_wh1   = alloc((size_t)N * DH * 2);       // wh1x / whc1
    const size_t o_h1a   = alloc((size_t)N * DH * 2);       // h1f / c1f
    const size_t o_h1b   = alloc((size_t)N * DH * 2);       // h1s / c1s
    const size_t o_whd1  = alloc((size_t)N * DH * 2);
    const size_t o_d1    = alloc((size_t)N * DH * 2);
    const size_t o_whd2  = alloc((size_t)N * DIN * 2);      // 24.6 MB
    size_t o_b64[8];
    for (int i = 0; i < 8; i++) o_b64[i] = alloc((size_t)N * DO * 2);

    u16* att    = (u16*)(ws + o_att);
    u32* maskF  = (u32*)(ws + o_maskF);
    u32* maskS  = (u32*)(ws + o_maskS);
    float* s1   = (float*)(ws + o_s1);
    float* s2   = (float*)(ws + o_s2);
    u16* wh1x   = (u16*)(ws + o_wh1);
    u16* whc1   = (u16*)(ws + o_wh1);
    u16* h1f    = (u16*)(ws + o_h1a);
    u16* c1f    = (u16*)(ws + o_h1a);
    u16* h1s    = (u16*)(ws + o_h1b);
    u16* c1s    = (u16*)(ws + o_h1b);
    u16* whd1   = (u16*)(ws + o_whd1);
    u16* d1b    = (u16*)(ws + o_d1);
    u16* whd2   = (u16*)(ws + o_whd2);
    u16* wh2f   = (u16*)(ws + o_b64[0]);
    u16* wh2s   = (u16*)(ws + o_b64[1]);
    u16* h2f    = (u16*)(ws + o_b64[2]);
    u16* h2s    = (u16*)(ws + o_b64[3]);
    u16* whc2f  = (u16*)(ws + o_b64[4]);
    u16* whc2s  = (u16*)(ws + o_b64[5]);
    u16* c2f    = (u16*)(ws + o_b64[6]);
    u16* c2s    = (u16*)(ws + o_b64[7]);

    auto grid = [](int M, int Nn) { return dim3((Nn + 63) / 64, (M + 63) / 64); };
    // A f32 (external act), B f32 (weight) -> bf16 internal
    auto gemm_ff = [&](const float* A, const float* B, u16* C, int M, int Nn, int K) {
        sgemm<true, true, false, false><<<grid(M, Nn), 256, 0, stream>>>(A, B, C, M, Nn, K);
    };
    // A internal bf16, B f32 weight -> bf16 internal
    auto gemm_hw = [&](const u16* A, const float* B, u16* C, int M, int Nn, int K) {
        sgemm<false, true, false, false><<<grid(M, Nn), 256, 0, stream>>>(A, B, C, M, Nn, K);
    };
    // att(bf16) @ Wh(bf16), ELU -> bf16 internal
    auto gemm_att = [&](const u16* A, const u16* B, u16* C, int M, int Nn, int K) {
        sgemm<false, false, true, false><<<grid(M, Nn), 256, 0, stream>>>(A, B, C, M, Nn, K);
    };
    // att(bf16) @ Wh(bf16), ELU -> f32 (recon into d_out)
    auto gemm_att_f32 = [&](const u16* A, const u16* B, float* C, int M, int Nn, int K) {
        sgemm<false, false, true, true><<<grid(M, Nn), 256, 0, stream>>>(A, B, C, M, Nn, K);
    };
    auto scores = [&](const u16* Wh, int ld, int F, const float* a) {
        scores_kernel<<<N, 256, 0, stream>>>(Wh, ld, F, a, s1, s2);
    };
    auto attb = [&](const u32* mask) {
        att_kernel<<<N, 256, 0, stream>>>(mask, s1, s2, att, N);
    };

    // ---- prep: bitmasks ----
    bitpack_kernel<<<(N * (N / 32) + 255) / 256, 256, 0, stream>>>(adjF, maskF, N * (N / 32));
    bitpack_kernel<<<(N * (N / 32) + 255) / 256, 256, 0, stream>>>(adjS, maskS, N * (N / 32));

    // ---- encoder layer 1 (Wh shared across both adjacencies) ----
    gemm_ff(x, We1, wh1x, N, DH, DIN);
    scores(wh1x, DH, DH, aE1);
    attb(maskF); gemm_att(att, wh1x, h1f, N, DH, N);
    attb(maskS); gemm_att(att, wh1x, h1s, N, DH, N);

    // ---- encoder layer 2 ----
    gemm_hw(h1f, We2, wh2f, N, DO, DH);
    scores(wh2f, DO, DO, aE2);
    attb(maskF); gemm_att(att, wh2f, h2f, N, DO, N);
    gemm_hw(h1s, We2, wh2s, N, DO, DH);
    scores(wh2s, DO, DO, aE2);
    attb(maskS); gemm_att(att, wh2s, h2s, N, DO, N);

    // ---- fuse -> emb_latent (f32 in d_out) + alpha ----
    fuse_kernel<<<N, 64, 0, stream>>>(h2f, h2s, Womega, Uomega, out_emb, out_alpha);

    // ---- decoder layer 1 (spatial adj); A = out_emb (f32) ----
    sgemm<true, true, false, false><<<grid(N, DH), 256, 0, stream>>>(
        out_emb, Wd1, whd1, N, DH, DO);
    scores(whd1, DH, DH, aD1);
    attb(maskS); gemm_att(att, whd1, d1b, N, DH, N);

    // ---- decoder layer 2 (spatial adj); recon (f32) into d_out ----
    gemm_hw(d1b, Wd2, whd2, N, DIN, DH);
    scores(whd2, DIN, DIN, aD2);
    attb(maskS); gemm_att_f32(att, whd2, out_recon, N, DIN, N);

    // ---- corr encoder layer 1 (A = recon f32 from d_out) ----
    gemm_ff(out_recon, We1, whc1, N, DH, DIN);
    scores(whc1, DH, DH, aE1);
    attb(maskF); gemm_att(att, whc1, c1f, N, DH, N);
    attb(maskS); gemm_att(att, whc1, c1s, N, DH, N);

    // ---- corr encoder layer 2 ----
    gemm_hw(c1f, We2, whc2f, N, DO, DH);
    scores(whc2f, DO, DO, aE2);
    attb(maskF); gemm_att(att, whc2f, c2f, N, DO, N);
    gemm_hw(c1s, We2, whc2s, N, DO, DH);
    scores(whc2s, DO, DO, aE2);
    attb(maskS); gemm_att(att, whc2s, c2s, N, DO, N);

    // ---- fuse -> corr (f32 in d_out) ----
    fuse_kernel<<<N, 64, 0, stream>>>(c2f, c2s, Womega, Uomega, out_corr, nullptr);
}